// Round 6
// baseline (100.135 us; speedup 1.0000x reference)
//
#include <hip/hip_runtime.h>

// 16-step spike recurrence, elementwise.
// z_t = (v_t > T_t) since (v-T)/(|v|+1) > 0 <=> v > T (denominator >= 1).
// R6: packed-f32 formulation. Keep z~ = -z in {0,-1}:
//   v = fma(z~, H_t, v)    (v -= H when spiked)   -> v_pk_fma_f32 pairs
//   o = fma(z~, -D_t, o)   (o += D when spiked)   -> v_pk_fma_f32 pairs
// Per elem/step: cmp + cndmask + 2 half-packed fmas = 3 VALU ops (was 4).
// 8x float4 per thread for MLP; nontemporal stores; exact-cover grid.

typedef float f32x4 __attribute__((ext_vector_type(4)));

__device__ __constant__ const float kH[16] = {
    -0.73437643f, 3.319645f,   2.1290164f,  3.6901689f,
    3.302721f,    3.2154958f,  2.9151256f,  3.1718695f,
    3.1084518f,   2.6179547f,  2.235003f,   1.2864777f,
    0.52327204f, -0.08344932f, -1.8249638f, 3.0859442f};

__device__ __constant__ const float kD[16] = {
    3.3848417f, -0.07072583f, 3.691287f,   3.3074934f,
    3.2120926f,  2.9196491f,  3.1727686f,  3.1054153f,
    2.621943f,   2.2355895f,  1.2878408f,  0.52468026f,
    0.12632068f, 0.14482783f, 0.3153498f,  0.13054803f};

__device__ __constant__ const float kT[16] = {
    3.1538513f, -1.0211663f,  1.3714716f,  1.0718397f,
    1.0049332f,  0.68078244f, 1.0151638f,  0.8858697f,
    0.4037103f,  0.01490025f, -0.90781677f, -1.6859558f,
    -1.9241625f, -2.0441303f, 0.279356f,   0.1315174f};

__device__ __forceinline__ f32x4 splat4(float s) {
    f32x4 r = {s, s, s, s};
    return r;
}

__device__ __forceinline__ f32x4 spike4(f32x4 v) {
    f32x4 zn = splat4(0.0f);   // zn = -z, in {0, -1}
    f32x4 o  = splat4(0.0f);
#pragma unroll
    for (int t = 0; t < 16; ++t) {
        // v -= z_{t-1} * H[t]  ==  v = fma(zn, H[t], v)
        v = __builtin_elementwise_fma(zn, splat4(kH[t]), v);
        zn.x = (v.x > kT[t]) ? -1.0f : 0.0f;
        zn.y = (v.y > kT[t]) ? -1.0f : 0.0f;
        zn.z = (v.z > kT[t]) ? -1.0f : 0.0f;
        zn.w = (v.w > kT[t]) ? -1.0f : 0.0f;
        // o += z_t * D[t]  ==  o = fma(zn, -D[t], o)
        o = __builtin_elementwise_fma(zn, splat4(-kD[t]), o);
    }
    return o;
}

__global__ __launch_bounds__(256) void spike_kernel(const f32x4* __restrict__ x,
                                                    f32x4* __restrict__ out,
                                                    int n4) {
    const int T = gridDim.x * blockDim.x;   // total threads
    int i = blockIdx.x * blockDim.x + threadIdx.x;

    // Main path: 8 independent float4 loads in flight per thread.
    for (; i + 7 * T < n4; i += 8 * T) {
        f32x4 a0 = x[i];
        f32x4 a1 = x[i + T];
        f32x4 a2 = x[i + 2 * T];
        f32x4 a3 = x[i + 3 * T];
        f32x4 a4 = x[i + 4 * T];
        f32x4 a5 = x[i + 5 * T];
        f32x4 a6 = x[i + 6 * T];
        f32x4 a7 = x[i + 7 * T];
        f32x4 r0 = spike4(a0);
        f32x4 r1 = spike4(a1);
        f32x4 r2 = spike4(a2);
        f32x4 r3 = spike4(a3);
        f32x4 r4 = spike4(a4);
        f32x4 r5 = spike4(a5);
        f32x4 r6 = spike4(a6);
        f32x4 r7 = spike4(a7);
        __builtin_nontemporal_store(r0, &out[i]);
        __builtin_nontemporal_store(r1, &out[i + T]);
        __builtin_nontemporal_store(r2, &out[i + 2 * T]);
        __builtin_nontemporal_store(r3, &out[i + 3 * T]);
        __builtin_nontemporal_store(r4, &out[i + 4 * T]);
        __builtin_nontemporal_store(r5, &out[i + 5 * T]);
        __builtin_nontemporal_store(r6, &out[i + 6 * T]);
        __builtin_nontemporal_store(r7, &out[i + 7 * T]);
    }
    // Tail (not taken for the bench shape: n4 = 16,777,216 divides evenly).
    for (; i < n4; i += T) {
        f32x4 r = spike4(x[i]);
        __builtin_nontemporal_store(r, &out[i]);
    }
}

extern "C" void kernel_launch(void* const* d_in, const int* in_sizes, int n_in,
                              void* d_out, int out_size, void* d_ws, size_t ws_size,
                              hipStream_t stream) {
    const float* x = (const float*)d_in[0];
    float* out = (float*)d_out;
    int n = in_sizes[0];          // 16*4096*1024 = 67,108,864
    int n4 = n >> 2;              // 16,777,216 float4

    const int block = 256;
    // One 8x-float4 chunk per thread: grid = n4 / (8*block) = 8192 blocks.
    int grid = (n4 + 8 * block - 1) / (8 * block);

    spike_kernel<<<grid, block, 0, stream>>>(
        (const f32x4*)x, (f32x4*)out, n4);
}